// Round 3
// baseline (959.133 us; speedup 1.0000x reference)
//
#include <hip/hip_runtime.h>

typedef unsigned short u16;
typedef short s8v __attribute__((ext_vector_type(8)));
typedef float f4v __attribute__((ext_vector_type(4)));
typedef _Float16 f16;
typedef _Float16 h2v __attribute__((ext_vector_type(2)));
typedef _Float16 h8v __attribute__((ext_vector_type(8)));

__device__ __forceinline__ float bf2f(u16 s) {
  unsigned u = ((unsigned)s) << 16;
  return __builtin_bit_cast(float, u);
}
__device__ __forceinline__ u16 f2bf(float f) {
  unsigned u = __builtin_bit_cast(unsigned, f);
  unsigned r = u + 0x7fffu + ((u >> 16) & 1u);  // RNE (no NaN here)
  return (u16)(r >> 16);
}
__device__ __forceinline__ s8v load8bf(const u16* p) {
  return __builtin_bit_cast(s8v, *(const uint4*)p);
}
__device__ __forceinline__ f4v mfma16(s8v a, s8v b, f4v c) {
  return __builtin_amdgcn_mfma_f32_16x16x32_bf16(a, b, c, 0, 0, 0);
}
// Pin a 128-bit fragment into registers: prevents remat/sink of the load.
__device__ __forceinline__ h8v pinh(h8v x) {
  union { h8v v; unsigned u[4]; } t;
  t.v = x;
  asm volatile("" : "+v"(t.u[0]), "+v"(t.u[1]), "+v"(t.u[2]), "+v"(t.u[3]));
  return t.v;
}
// LDS-only barrier: __syncthreads() drains vmcnt(0) (global stores/prefetch);
// the scan only needs LDS ordering across the double-buffered images.
__device__ __forceinline__ void barrier_lds() {
  asm volatile("s_waitcnt lgkmcnt(0)\n\ts_barrier" ::: "memory");
}
// lane(2j) <-> lane(2j+1) exchange (BitMode xor=1, and=0x1F)
__device__ __forceinline__ float swz_xor1(float x) {
  int i = __builtin_bit_cast(int, x);
  i = __builtin_amdgcn_ds_swizzle(i, 0x041F);
  return __builtin_bit_cast(float, i);
}
__device__ __forceinline__ h2v pr(h8v v, int e) {
  union { h8v v; h2v p[4]; } t;
  t.v = v;
  return t.p[e];
}
__device__ __forceinline__ float fdot2(h2v a, h2v b, float c) {
  return __builtin_amdgcn_fdot2(a, b, c, false);
}
// 8 consecutive f32 -> bf16 hi + bf16 lo fragments (split precision)
__device__ __forceinline__ void cvt8(const float* p, s8v& hi, s8v& lo) {
  float4 x0 = ((const float4*)p)[0];
  float4 x1 = ((const float4*)p)[1];
  float v[8] = {x0.x, x0.y, x0.z, x0.w, x1.x, x1.y, x1.z, x1.w};
  union { s8v v; u16 a[8]; } H, L;
#pragma unroll
  for (int i = 0; i < 8; ++i) {
    u16 h = f2bf(v[i]);
    H.a[i] = h;
    L.a[i] = f2bf(v[i] - bf2f(h));
  }
  hi = H.v;
  lo = L.v;
}
// tanh(x) = 1 - 2/(1+e^{2x}) via hw exp2/rcp (~1e-6 abs err)
__device__ __forceinline__ float fast_tanh(float x) {
  float t = __builtin_amdgcn_exp2f(x * 2.885390081777927f);
  return 1.f - 2.f * __builtin_amdgcn_rcpf(t + 1.f);
}
__device__ __forceinline__ float fast_sigmoid(float x) {
  float t = __builtin_amdgcn_exp2f(x * -1.4426950408889634f);
  return __builtin_amdgcn_rcpf(1.f + t);
}

// ---------------------------------------------------------------------------
// Prep: scan weights {g_Whh0, g_Wih1, g_Whh1} -> f16 row-major; e-weights ->
// bf16; GEMM weights -> bf16 hi/lo split pairs; mask -> f32 table [s][b].
// ---------------------------------------------------------------------------
__global__ void k_prep(const float* __restrict__ W0, const float* __restrict__ Wx,
                       const float* __restrict__ W1, f16* __restrict__ w0h,
                       f16* __restrict__ wxh, f16* __restrict__ w1h,
                       const float* __restrict__ E0, const float* __restrict__ E1,
                       const float* __restrict__ E2, u16* __restrict__ B0,
                       u16* __restrict__ B1, u16* __restrict__ B2,
                       const float* __restrict__ gW0, u16* __restrict__ gw0hi,
                       u16* __restrict__ gw0lo,
                       const float* __restrict__ hW, u16* __restrict__ hWhi,
                       u16* __restrict__ hWlo, const float* __restrict__ dW,
                       u16* __restrict__ dWhi, u16* __restrict__ dWlo,
                       const int* __restrict__ mask, float* __restrict__ maskfb) {
  int t = blockIdx.x * 256 + threadIdx.x;  // 598016 total
  if (t < 196608) {
    int which = t >> 16;
    int idx = t & 65535;
    const float* src = which == 0 ? W0 : (which == 1 ? Wx : W1);
    f16* dst = which == 0 ? w0h : (which == 1 ? wxh : w1h);
    dst[idx] = (f16)src[idx];
  } else if (t < 393216) {
    int c = t - 196608;
    int which = c >> 16;
    int idx = c & 65535;
    const float* src = which == 0 ? E0 : (which == 1 ? E1 : E2);
    u16* dst = which == 0 ? B0 : (which == 1 ? B1 : B2);
    dst[idx] = f2bf(src[idx]);
  } else if (t < 589824) {
    const float* src;
    u16 *dhi, *dlo;
    int idx;
    if (t < 524288) { idx = t - 393216; src = gW0; dhi = gw0hi; dlo = gw0lo; }
    else if (t < 557056) { idx = t - 524288; src = hW; dhi = hWhi; dlo = hWlo; }
    else { idx = t - 557056; src = dW; dhi = dWhi; dlo = dWlo; }
    float v = src[idx];
    u16 h = f2bf(v);
    dhi[idx] = h;
    dlo[idx] = f2bf(v - bf2f(h));
  } else if (t < 598016) {
    int c = t - 589824;  // c = s*16 + b
    int s = c >> 4, b = c & 15;
    maskfb[c] = (s == 0) ? 1.f : (float)mask[b * 511 + s - 1];
  }
}

// ---------------------------------------------------------------------------
// xw0 = X @ g_Wih0^T + bih0 + bhh0 (split-bf16, pre-split W). grid (128,4)x256.
// ---------------------------------------------------------------------------
__launch_bounds__(256)
__global__ void k_xw0(const float* __restrict__ input, const float* __restrict__ sentinel,
                      const u16* __restrict__ Whi, const u16* __restrict__ Wlo,
                      const float* __restrict__ b1, const float* __restrict__ b2,
                      float* __restrict__ outxw) {
  const int l = threadIdx.x & 63;
  const int wv = threadIdx.x >> 6;
  const int l15 = l & 15, q = l >> 4;
  const int row0 = blockIdx.x * 64 + wv * 16;
  const int col0 = blockIdx.y * 64;
  int row = row0 + l15;
  int s = row & 511, b = row >> 9;
  const float* aptr = (s == 0) ? sentinel : input + (((size_t)(b * 511 + s - 1)) << 9);
  f4v acc[4];
#pragma unroll
  for (int i = 0; i < 4; ++i) acc[i] = (f4v){0.f, 0.f, 0.f, 0.f};
#pragma unroll
  for (int kt = 0; kt < 16; ++kt) {
    int k0 = kt * 32 + q * 8;
    s8v ah, al;
    cvt8(aptr + k0, ah, al);
#pragma unroll
    for (int nt = 0; nt < 4; ++nt) {
      int j = col0 + nt * 16 + l15;
      s8v wh = load8bf(Whi + ((size_t)j << 9) + k0);
      s8v wl = load8bf(Wlo + ((size_t)j << 9) + k0);
      acc[nt] = mfma16(ah, wh, acc[nt]);
      acc[nt] = mfma16(al, wh, acc[nt]);
      acc[nt] = mfma16(ah, wl, acc[nt]);
    }
  }
#pragma unroll
  for (int nt = 0; nt < 4; ++nt) {
    int col = col0 + nt * 16 + l15;
    float bias = b1[col] + b2[col];
#pragma unroll
    for (int r = 0; r < 4; ++r) {
      int rr = row0 + q * 4 + r;
      outxw[((size_t)rr << 8) + col] = acc[nt][r] + bias;
    }
  }
}

// ---------------------------------------------------------------------------
// Merged head/dep tag GEMM: C = elu(A @ W^T + b); z selects head/dep.
// grid (N/64, J/64, 2) x 256.
// ---------------------------------------------------------------------------
__launch_bounds__(256)
__global__ void k_gemm2(const float* __restrict__ A,
                        const u16* __restrict__ WhiA, const u16* __restrict__ WloA,
                        const float* __restrict__ bA, float* __restrict__ outA,
                        const u16* __restrict__ WhiB, const u16* __restrict__ WloB,
                        const float* __restrict__ bB, float* __restrict__ outB,
                        int K, int J) {
  const u16* Whi = blockIdx.z ? WhiB : WhiA;
  const u16* Wlo = blockIdx.z ? WloB : WloA;
  const float* b1 = blockIdx.z ? bB : bA;
  float* outf = blockIdx.z ? outB : outA;
  const int l = threadIdx.x & 63;
  const int wv = threadIdx.x >> 6;
  const int l15 = l & 15, q = l >> 4;
  const int row0 = blockIdx.x * 64 + wv * 16;
  const int col0 = blockIdx.y * 64;
  const float* aptr = A + (size_t)(row0 + l15) * K;
  f4v acc[4];
#pragma unroll
  for (int i = 0; i < 4; ++i) acc[i] = (f4v){0.f, 0.f, 0.f, 0.f};
  const int nkt = K >> 5;
  for (int kt = 0; kt < nkt; ++kt) {
    int k0 = kt * 32 + q * 8;
    s8v ah, al;
    cvt8(aptr + k0, ah, al);
#pragma unroll
    for (int nt = 0; nt < 4; ++nt) {
      int j = col0 + nt * 16 + l15;
      s8v wh = load8bf(Whi + (size_t)j * K + k0);
      s8v wl = load8bf(Wlo + (size_t)j * K + k0);
      acc[nt] = mfma16(ah, wh, acc[nt]);
      acc[nt] = mfma16(al, wh, acc[nt]);
      acc[nt] = mfma16(ah, wl, acc[nt]);
    }
  }
#pragma unroll
  for (int nt = 0; nt < 4; ++nt) {
    int col = col0 + nt * 16 + l15;
    float bias = b1[col];
#pragma unroll
    for (int r = 0; r < 4; ++r) {
      int rr = row0 + q * 4 + r;
      float v = acc[nt][r] + bias;
      v = v > 0.f ? v : (__builtin_amdgcn_exp2f(v * 1.4426950408889634f) - 1.f);
      outf[(size_t)rr * J + col] = v;
    }
  }
}

// ---------------------------------------------------------------------------
// FUSED two-layer RNN scan v5: VALU dot2, NO MFMA.
//
// R0-R2 counter model: the MFMA scan was matrix-pipe bound (59% busy on
// active CUs) doing 16x-REDUNDANT work (A-operand = h broadcast to all 16
// M-rows; only row 0 used). 384 MFMA x ~4cyc = 1506 cyc/step of pipe time
// for 196K real MACs. v_dot2_f32_f16 does the same real work with ZERO
// redundancy: per wave 32 cols x 3 matvecs, 2 lanes/output (k-halves),
// 192 dot2/lane/step -> 768 cyc/SIMD (2 waves) ~ half the MFMA pipe time.
// Also kills acc-init movs, C-reg0 injection, f2bf. h + weights in f16
// (MORE precise than the old bf16 path; old Wxb was hi-bf16-only).
// Pair combine: ds_swizzle xor1 + add. Weights pinned: 48 h8v = 192 VGPR.
// Pipeline (unchanged), one barrier per step:
//   step g: h1[g]   = tanh(xw1[g] + Whh0*h1[g-1])       (rec1)
//           xw2[g-1]= Wih1*h1[g-1] + bias2              (same h1 reads!)
//           h2[g-2] = tanh(xw2[g-2] + Whh1*h2[g-3])     (rec2) -> gs out
// ---------------------------------------------------------------------------
__launch_bounds__(512, 2)
__global__ void k_scan_d(const float* __restrict__ xw, const f16* __restrict__ W0h,
                         const f16* __restrict__ Wxh, const f16* __restrict__ W1h,
                         const float* __restrict__ bih1, const float* __restrict__ bhh1,
                         float* __restrict__ outf, const float* __restrict__ maskf) {
  __shared__ f16 H1[2][256];
  __shared__ f16 H2[2][256];
  __shared__ float XW2[2][256];
  __shared__ float mtab[512];
  const int tid = threadIdx.x;
  const int l = tid & 63, wv = tid >> 6;  // wv 0..7
  const int jw = l >> 1, p = l & 1;       // output-in-wave, k-half
  const int j = wv * 32 + jw;             // global output col
  const int b = blockIdx.x;               // batch row

  // pinned stationary weights: W[j][p*128 .. +128) for 3 matrices
  h8v w0[16], wx[16], w1[16];
  {
    const size_t base = ((size_t)j << 8) + (p << 7);
#pragma unroll
    for (int i = 0; i < 16; ++i) {
      w0[i] = pinh(*(const h8v*)(W0h + base + i * 8));
      wx[i] = pinh(*(const h8v*)(Wxh + base + i * 8));
      w1[i] = pinh(*(const h8v*)(W1h + base + i * 8));
    }
  }
  if (tid < 256) {
    H1[0][tid] = (f16)0.f; H1[1][tid] = (f16)0.f;
    H2[0][tid] = (f16)0.f; H2[1][tid] = (f16)0.f;
    XW2[0][tid] = 0.f; XW2[1][tid] = 0.f;
  }
  if (tid < 512) mtab[tid] = maskf[tid * 16 + b];
  const float b2v = bih1[j] + bhh1[j];
  __syncthreads();

  const size_t nbase = (size_t)b << 9;
  const float* xrow = xw + (nbase << 8);
  const int hoff = p << 7;  // this lane's k-half offset (elements)

  float xA = xrow[j], xB = xrow[256 + j];

  auto STEP = [&](int g, int par, float xc) {
    const f16* H1r = &H1[par][0] + hoff;
    const f16* H2r = &H2[par][0] + hoff;
    float xwprev = XW2[par][j];
    float s1a = 0.f, s1b = 0.f, sxa = 0.f, sxb = 0.f;
    float s2[4] = {0.f, 0.f, 0.f, 0.f};
    // rec1 + xw2 share the h1 reads; chunked to bound live h regs
#pragma unroll
    for (int c = 0; c < 4; ++c) {
      h8v h[4];
#pragma unroll
      for (int u = 0; u < 4; ++u) h[u] = *(const h8v*)(H1r + c * 32 + u * 8);
#pragma unroll
      for (int u = 0; u < 4; ++u)
#pragma unroll
        for (int e = 0; e < 4; ++e) {
          h2v hp = pr(h[u], e);
          if (e & 1) {
            s1b = fdot2(hp, pr(w0[c * 4 + u], e), s1b);
            sxb = fdot2(hp, pr(wx[c * 4 + u], e), sxb);
          } else {
            s1a = fdot2(hp, pr(w0[c * 4 + u], e), s1a);
            sxa = fdot2(hp, pr(wx[c * 4 + u], e), sxa);
          }
        }
    }
    // rec2: 4 partial chains
#pragma unroll
    for (int c = 0; c < 4; ++c) {
      h8v h[4];
#pragma unroll
      for (int u = 0; u < 4; ++u) h[u] = *(const h8v*)(H2r + c * 32 + u * 8);
#pragma unroll
      for (int u = 0; u < 4; ++u)
#pragma unroll
        for (int e = 0; e < 4; ++e)
          s2[e] = fdot2(pr(h[u], e), pr(w1[c * 4 + u], e), s2[e]);
    }
    // pair combines (lane 2j holds k<128, lane 2j+1 holds k>=128)
    float t1 = s1a + s1b, tx = sxa + sxb;
    float t2 = (s2[0] + s2[1]) + (s2[2] + s2[3]);
    t1 += swz_xor1(t1);
    tx += swz_xor1(tx);
    t2 += swz_xor1(t2);
    float h1n = fast_tanh(xc + t1);
    float xwn = b2v + tx;
    if (p == 0) {
      H1[1 - par][j] = (f16)h1n;
      XW2[1 - par][j] = xwn;
    }
    if (g >= 2) {
      int t = g - 2;
      float h2n = fast_tanh(xwprev + t2);
      if (p == 0) {
        H2[1 - par][j] = (f16)h2n;
        outf[((nbase + (size_t)t) << 8) + j] = h2n * mtab[t];
      }
    }
  };

  for (int g = 0; g < 514; g += 2) {
    STEP(g, 0, xA);
    int sp = g + 2 > 511 ? 511 : g + 2;
    xA = xrow[(sp << 8) + j];
    barrier_lds();
    STEP(g + 1, 1, xB);
    int sq = g + 3 > 511 ? 511 : g + 3;
    xB = xrow[(sq << 8) + j];
    barrier_lds();
  }
}

// ---------------------------------------------------------------------------
// Encoder: 32 steps, 32 rows/wg, 512 threads = 8 waves; weights resident;
// h0/h1 bf16 in LDS.
// ---------------------------------------------------------------------------
__launch_bounds__(512, 2)
__global__ void k_enc(const float* __restrict__ gs,
                      const u16* __restrict__ W0b, const u16* __restrict__ W1b,
                      const u16* __restrict__ W2b, const float* __restrict__ wih0,
                      const float* __restrict__ bih0, const float* __restrict__ bhh0,
                      const float* __restrict__ bih1, const float* __restrict__ bhh1,
                      const float* __restrict__ clsW, const float* __restrict__ clsb,
                      float* __restrict__ Ab) {
  __shared__ __align__(16) u16 hA0[32 * 264];
  __shared__ __align__(16) u16 hA1[32 * 264];
  __shared__ float xe[32];
  __shared__ float b0v[256], w0v[256], b1v[256], clsv[256];
  __shared__ float clsbs;
  const int tid = threadIdx.x;
  const int n0 = blockIdx.x * 32;

  for (int c = tid; c < 8192; c += 512) {
    int row = c >> 8, col = c & 255;
    hA0[row * 264 + col] = f2bf(gs[(((size_t)(n0 + row)) << 8) + col]);
    hA1[row * 264 + col] = 0;
  }
  if (tid < 256) {
    b0v[tid] = bih0[tid] + bhh0[tid];
    w0v[tid] = wih0[tid];
    b1v[tid] = bih1[tid] + bhh1[tid];
    clsv[tid] = clsW[tid];
  }
  if (tid < 32) xe[tid] = 1.0f;
  if (tid == 0) clsbs = clsb[0];

  const int l = tid & 63, wv = tid >> 6;
  const int l15 = l & 15, q = l >> 4;
  const int colbase = wv * 32;

  s8v w0[2][8], w1[2][8], w2[2][8];
#pragma unroll
  for (int nt = 0; nt < 2; ++nt) {
    int jj = colbase + nt * 16 + l15;
#pragma unroll
    for (int kt = 0; kt < 8; ++kt) {
      int off = (jj << 8) + kt * 32 + q * 8;
      w0[nt][kt] = load8bf(W0b + off);
      w1[nt][kt] = load8bf(W1b + off);
      w2[nt][kt] = load8bf(W2b + off);
    }
  }
  __syncthreads();

  for (int m = 0; m < 32; ++m) {
    f4v acc[2][2];
#pragma unroll
    for (int mt = 0; mt < 2; ++mt)
#pragma unroll
      for (int nt = 0; nt < 2; ++nt) acc[mt][nt] = (f4v){0.f, 0.f, 0.f, 0.f};
#pragma unroll
    for (int kt = 0; kt < 8; ++kt) {
#pragma unroll
      for (int mt = 0; mt < 2; ++mt) {
        s8v a = __builtin_bit_cast(s8v, *(const uint4*)&hA0[(mt * 16 + l15) * 264 + kt * 32 + q * 8]);
        acc[mt][0] = mfma16(a, w0[0][kt], acc[mt][0]);
        acc[mt][1] = mfma16(a, w0[1][kt], acc[mt][1]);
      }
    }
    __syncthreads();
#pragma unroll
    for (int nt = 0; nt < 2; ++nt) {
      int col = colbase + nt * 16 + l15;
      float wc = w0v[col], bc = b0v[col];
#pragma unroll
      for (int mt = 0; mt < 2; ++mt)
#pragma unroll
        for (int r = 0; r < 4; ++r) {
          int row = mt * 16 + q * 4 + r;
          float v = acc[mt][nt][r] + xe[row] * wc + bc;
          hA0[row * 264 + col] = f2bf(fast_tanh(v));
        }
    }
    __syncthreads();
#pragma unroll
    for (int mt = 0; mt < 2; ++mt)
#pragma unroll
      for (int nt = 0; nt < 2; ++nt) acc[mt][nt] = (f4v){0.f, 0.f, 0.f, 0.f};
#pragma unroll
    for (int kt = 0; kt < 8; ++kt) {
#pragma unroll
      for (int mt = 0; mt < 2; ++mt) {
        s8v a0 = __builtin_bit_cast(s8v, *(const uint4*)&hA0[(mt * 16 + l15) * 264 + kt * 32 + q * 8]);
        s8v a1 = __builtin_bit_cast(s8v, *(const uint4*)&hA1[(mt * 16 + l15) * 264 + kt * 32 + q * 8]);
        acc[mt][0] = mfma16(a0, w1[0][kt], acc[mt][0]);
        acc[mt][1] = mfma16(a0, w1[1][kt], acc[mt][1]);
        acc[mt][0] = mfma16(a1, w2[0][kt], acc[mt][0]);
        acc[mt][1] = mfma16(a1, w2[1][kt], acc[mt][1]);
      }
    }
    __syncthreads();
#pragma unroll
    for (int nt = 0; nt < 2; ++nt) {
      int col = colbase + nt * 16 + l15;
      float bc = b1v[col];
#pragma unroll
      for (int mt = 0; mt < 2; ++mt)
#pragma unroll
        for (int r = 0; r < 4; ++r) {
          int row = mt * 16 + q * 4 + r;
          float v = acc[mt][nt][r] + bc;
          hA1[row * 264 + col] = f2bf(fast_tanh(v));
        }
    }
    __syncthreads();
    if (tid < 256) {
      int row = tid >> 3, seg = tid & 7;
      float sum = 0.f;
#pragma unroll
      for (int u = 0; u < 4; ++u) {
        int col = seg * 32 + u * 8;
#pragma unroll
        for (int e = 0; e < 8; ++e) sum += bf2f(hA1[row * 264 + col + e]) * clsv[col + e];
      }
      sum += __shfl_down(sum, 4, 8);
      sum += __shfl_down(sum, 2, 8);
      sum += __shfl_down(sum, 1, 8);
      if (seg == 0) {
        float pp = fast_sigmoid(sum + clsbs);
        xe[row] = pp;
        Ab[(((size_t)(n0 + row)) << 5) + m] = pp;
      }
    }
    __syncthreads();
  }
}

// ---------------------------------------------------------------------------
// arc_logits[b][j][i] = (j>=max(0,i-32) && j<i) ? Ab[(b*512+i)*32 + j-start] : 0
// ---------------------------------------------------------------------------
__global__ void k_arc(const float* __restrict__ Ab, float* __restrict__ out2) {
  int t = blockIdx.x * 256 + threadIdx.x;  // 4194304 total
  int b = t >> 18;
  int rem = t & 262143;
  int j = rem >> 9, i = rem & 511;
  int start = i - 32;
  if (start < 0) start = 0;
  float v = 0.f;
  if (j >= start && j < i) v = Ab[((((size_t)b << 9) + i) << 5) + (j - start)];
  out2[t] = v;
}

// ---------------------------------------------------------------------------
extern "C" void kernel_launch(void* const* d_in, const int* in_sizes, int n_in,
                              void* d_out, int out_size, void* d_ws, size_t ws_size,
                              hipStream_t stream) {
  const float* input    = (const float*)d_in[0];
  const float* sentinel = (const float*)d_in[1];
  const float* g_Wih0   = (const float*)d_in[2];
  const float* g_Whh0   = (const float*)d_in[3];
  const float* g_bih0   = (const float*)d_in[4];
  const float* g_bhh0   = (const float*)d_in[5];
  const float* g_Wih1   = (const float*)d_in[6];
  const float* g_Whh1   = (const float*)d_in[7];
  const float* g_bih1   = (const float*)d_in[8];
  const float* g_bhh1   = (const float*)d_in[9];
  const float* e_Wih0   = (const float*)d_in[10];
  const float* e_Whh0   = (const float*)d_in[11];
  const float* e_bih0   = (const float*)d_in[12];
  const float* e_bhh0   = (const float*)d_in[13];
  const float* e_Wih1   = (const float*)d_in[14];
  const float* e_Whh1   = (const float*)d_in[15];
  const float* e_bih1   = (const float*)d_in[16];
  const float* e_bhh1   = (const float*)d_in[17];
  const float* cls_W    = (const float*)d_in[18];
  const float* cls_b    = (const float*)d_in[19];
  const float* head_W   = (const float*)d_in[20];
  const float* head_b   = (const float*)d_in[21];
  const float* dep_W    = (const float*)d_in[22];
  const float* dep_b    = (const float*)d_in[23];
  const int* mask       = (const int*)d_in[24];

  float* out = (float*)d_out;
  char* ws = (char*)d_ws;
  float* xw_buf = (float*)ws;                                  // 8 MB
  float* gsb    = (float*)(ws + (16u << 20));                  // 8 MB
  float* Ab     = (float*)(ws + (24u << 20));                  // 1 MB
  size_t o = (25u << 20);
  f16* w0h     = (f16*)(ws + o); o += 128u << 10;
  f16* wxh     = (f16*)(ws + o); o += 128u << 10;
  f16* w1h     = (f16*)(ws + o); o += 128u << 10;
  float* maskfb= (float*)(ws + o); o += 32u << 10;
  u16* eb0     = (u16*)(ws + o); o += 128u << 10;
  u16* eb1     = (u16*)(ws + o); o += 128u << 10;
  u16* eb2     = (u16*)(ws + o); o += 128u << 10;
  u16* gw0hi   = (u16*)(ws + o); o += 256u << 10;
  u16* gw0lo   = (u16*)(ws + o); o += 256u << 10;
  u16* hWhi    = (u16*)(ws + o); o += 64u << 10;
  u16* hWlo    = (u16*)(ws + o); o += 64u << 10;
  u16* dWhi    = (u16*)(ws + o); o += 64u << 10;
  u16* dWlo    = (u16*)(ws + o); o += 64u << 10;

  k_prep<<<2336, 256, 0, stream>>>(g_Whh0, g_Wih1, g_Whh1, w0h, wxh, w1h,
                                   e_Whh0, e_Wih1, e_Whh1, eb0, eb1, eb2,
                                   g_Wih0, gw0hi, gw0lo, head_W, hWhi, hWlo,
                                   dep_W, dWhi, dWlo, mask, maskfb);
  k_xw0<<<dim3(128, 4), 256, 0, stream>>>(input, sentinel, gw0hi, gw0lo, g_bih0, g_bhh0,
                                          xw_buf);
  k_scan_d<<<16, 512, 0, stream>>>(xw_buf, w0h, wxh, w1h, g_bih1, g_bhh1,
                                   gsb, maskfb);
  k_gemm2<<<dim3(128, 2, 2), 256, 0, stream>>>(gsb, hWhi, hWlo, head_b, out,
                                               dWhi, dWlo, dep_b, out + 1048576,
                                               256, 128);
  k_enc<<<256, 512, 0, stream>>>(gsb, eb0, eb1, eb2, e_Wih0, e_bih0, e_bhh0,
                                 e_bih1, e_bhh1, cls_W, cls_b, Ab);
  k_arc<<<16384, 256, 0, stream>>>(Ab, out + 2097152);
}